// Round 1
// baseline (1953.063 us; speedup 1.0000x reference)
//
#include <hip/hip_runtime.h>
#include <hip/hip_bf16.h>

// ACOPF Gauss-Newton, matrix-free CGLS, single-workgroup LDS-resident solver.
// R15: determinism + trajectory-fidelity pass.
//  - Root cause of the R14 bench failure: nondeterministic LDS fp32 atomics
//    (gb_ diag accumulation) and nondeterministic edge-slot order (cur_
//    atomicAdd) re-roll fp32 rounding each run; the 10-step GN trajectory is
//    chaotic, so absmax flips between ~0.19 (pass) and ~0.42 (fail).
//  - Fix: per-line ranks precomputed in setup_k -> deterministic CSR placement
//    (no cur_ atomics); per-edge diag contributions staged in ev_ and
//    row-summed in slot order (no fp32 atomics). Bit-reproducible.
//  - Fidelity: line Y built in fp64 (correctly-rounded fp32, matches ref's
//    complex64 build), fp64 sincos for bus angles (replaces __sincosf's
//    few-ulp error), fp64 x-state, fp64 accumulation in outer residual /
//    gradient rowsums. Inner CG loop identical to R12 (fp32, 4 phases,
//    fp64 scalars, RR every 64, 2x2 block-Jacobi, rel tol 1e-10 + abs floor).
// Prior best measured (R12 structure): 1871 us.

#define NBUS 1000
#define NLINE 2000
#define NE   (2*NLINE)
#define NGEN 100
#define NLOAD 500
#define NTH 1024
#define NWAVE (NTH/64)
#define MAXSTEPS 10
#define KCG_MAX 600
#define RIDGE_F 1e-6f
#define TOL_REL 1e-10

struct Ws {
  int   vm_pos[NBUS];
  int   va_pos[NBUS];
  float Pspec[NBUS];
  float Qspec[NBUS];
  float Vgb[NBUS];
  int   rank_f[NLINE];   // # earlier lines incident to lf[l]
  int   rank_t[NLINE];   // # earlier lines incident to lt[l]
};

__device__ __forceinline__ float rdf(const void* p, int i, int bf) {
  if (bf) {
    unsigned int u = ((unsigned int)(((const unsigned short*)p)[i])) << 16;
    return __uint_as_float(u);
  }
  return ((const float*)p)[i];
}
__device__ __forceinline__ void wrf(void* p, int i, float v, int bf) {
  if (bf) {
    unsigned int u = __float_as_uint(v);
    unsigned int r = (u + 0x7fffu + ((u >> 16) & 1u)) >> 16;  // RNE
    ((unsigned short*)p)[i] = (unsigned short)r;
  } else {
    ((float*)p)[i] = v;
  }
}
__device__ __forceinline__ int detect_bf(const void* p) {
  const unsigned short* h = (const unsigned short*)p;
  int ok = 1;
#pragma unroll
  for (int i = 0; i < 8; ++i) {
    float v = __uint_as_float(((unsigned int)h[i]) << 16);
    ok &= (v > 0.25f && v < 8.0f) ? 1 : 0;
  }
  return ok;
}
__device__ __forceinline__ int lbound(const int* a, int n, int v) {
  int lo = 0, hi = n;
  while (lo < hi) { int m = (lo + hi) >> 1; if (a[m] < v) lo = m + 1; else hi = m; }
  return lo;
}

struct In {
  const void *lg, *lb, *tp, *sh, *ch;
  const int *lf, *lt;
  int bf;
};
struct LineY { int f, t; float ffr, ffi, ttr, tti, ftr, fti, tfr, tfi; };

// fp64 build -> correctly-rounded fp32 Y entries (setup-only, runs twice/thread)
__device__ __forceinline__ LineY line_y(const In& I, int l) {
  LineY L;
  double g = rdf(I.lg, l, I.bf), b = rdf(I.lb, l, I.bf);
  double t = rdf(I.tp, l, I.bf), s = rdf(I.sh, l, I.bf);
  double c = rdf(I.ch, l, I.bf) * 0.5;
  double sn, cs;
  sincos(s, &sn, &cs);
  double it = 1.0 / t, it2 = it * it;
  L.f = I.lf[l]; L.t = I.lt[l];
  L.ffr = (float)(g * it2);                 L.ffi = (float)((b + c) * it2);
  L.ttr = (float)g;                         L.tti = (float)(b + c);
  L.ftr = (float)(-(g * cs - b * sn) * it); L.fti = (float)(-(g * sn + b * cs) * it);
  L.tfr = (float)(-(g * cs + b * sn) * it); L.tfi = (float)(-(b * cs - g * sn) * it);
  return L;
}

// fp32 block sum: 6-shuffle wave reduce, wave partials to LDS, tail = 4
// independent float4 reads. Deterministic (fixed order).
__device__ __forceinline__ float blk_sumf(float v, float* red) {
#pragma unroll
  for (int o = 32; o > 0; o >>= 1) v += __shfl_down(v, o, 64);
  if ((threadIdx.x & 63) == 0) red[threadIdx.x >> 6] = v;
  __syncthreads();
  const float4* r4 = (const float4*)red;
  float s = 0.f;
#pragma unroll
  for (int w = 0; w < NWAVE / 4; ++w) {
    float4 t = r4[w];
    s += t.x; s += t.y; s += t.z; s += t.w;
  }
  return s;
}

__global__ void setup_k(const void* lg, const void* Pg, const void* Vg,
                        const void* Pl, const void* Ql,
                        const int* gen_b, const int* load_b, const int* refp,
                        const int* lf, const int* lt,
                        Ws* __restrict__ W) {
  __shared__ int slf[NLINE], slt[NLINE];
  int bf = detect_bf(lg);
  int t = blockIdx.x * blockDim.x + threadIdx.x;
  for (int i = threadIdx.x; i < NLINE; i += blockDim.x) { slf[i] = lf[i]; slt[i] = lt[i]; }
  __syncthreads();
  int ref = refp[0];
  if (t < NBUS) {
    int gl = lbound(gen_b, NGEN, t);
    int isg = (gl < NGEN && gen_b[gl] == t) ? 1 : 0;
    int ll = lbound(load_b, NLOAD, t);
    int isl = (ll < NLOAD && load_b[ll] == t) ? 1 : 0;
    W->vm_pos[t] = isg ? -1 : (t - gl);
    W->va_pos[t] = (t == ref) ? -1 : (t - ((t > ref) ? 1 : 0));
    float ps = 0.f, qs = 0.f;
    if (isg) ps += rdf(Pg, gl, bf);
    if (isl) { ps += rdf(Pl, ll, bf); qs += rdf(Ql, ll, bf); }
    W->Pspec[t] = ps;
    W->Qspec[t] = qs;
    W->Vgb[t] = isg ? rdf(Vg, gl, bf) : 1.0f;
  }
  if (t < NLINE) {
    int f = slf[t], tt = slt[t], rf = 0, rt = 0;
    for (int l = 0; l < t; ++l) {
      int a = slf[l], b = slt[l];
      rf += (a == f) + (b == f);
      rt += (a == tt) + (b == tt);
    }
    W->rank_f[t] = rf;
    W->rank_t[t] = rt;
  }
}

__global__ void __launch_bounds__(NTH)
solver_k(const void* lg, const void* lb, const void* shg, const void* shb,
         const void* tp, const void* sh, const void* ch, const void* limits,
         const int* lf, const int* lt, const int* gen_b, const int* refp,
         const Ws* __restrict__ W, void* __restrict__ out) {
  __shared__ int rs_[NBUS + 1];
  __shared__ unsigned short cidx_[NE];  // edge -> source-bus index
  __shared__ float2 fwd_[NE];           // Y_kj for edge in row k
  __shared__ float2 rev_[NE];           // Y_jk
  __shared__ float2 ev_[NE];            // per-edge values (overlaid at setup)
  __shared__ float2 stp_[NBUS];         // T(p_{k-1}) per bus
  __shared__ float2 stz_[NBUS];         // T(z_k) per bus
  __shared__ float2 sts_[NBUS];         // seed staging (q seeds / RR / outer)
  __shared__ float2 ab_[NBUS];          // per-bus V (re,im)
  __shared__ float2 mk_[NBUS];          // (mnr, mng)
  __shared__ __align__(16) float red_[2][NWAVE];

  const int tid = threadIdx.x;
  const bool own = (tid < NBUS);
  In I;
  I.lg = lg; I.lb = lb; I.tp = tp; I.sh = sh; I.ch = ch;
  I.lf = lf; I.lt = lt;
  I.bf = detect_bf(lg);
  const int bf = I.bf;

  // setup scratch overlaid on ev_ (dead after the scan completes)
  int* scanA = (int*)ev_;
  int* scanB = ((int*)ev_) + NTH;

  int vp = -1, ap = -1;
  float mng = 0.f, mnr = 0.f, Pspec = 0.f, Qspec = 0.f, Vgb = 1.f;
  if (own) {
    vp = W->vm_pos[tid]; ap = W->va_pos[tid];
    mng = (vp >= 0) ? 1.f : 0.f;
    mnr = (ap >= 0) ? 1.f : 0.f;
    Pspec = W->Pspec[tid]; Qspec = W->Qspec[tid]; Vgb = W->Vgb[tid];
    mk_[tid] = make_float2(mnr, mng);
  }
  scanA[tid] = 0;
  __syncthreads();
  for (int l = tid; l < NLINE; l += NTH) {   // integer atomics: order-independent
    atomicAdd(&scanA[lf[l]], 1);
    atomicAdd(&scanA[lt[l]], 1);
  }
  __syncthreads();
  {
    int* src = scanA; int* dst = scanB;
    for (int off = 1; off < NTH; off <<= 1) {
      int v = src[tid] + ((tid >= off) ? src[tid - off] : 0);
      dst[tid] = v;
      __syncthreads();
      int* t = src; src = dst; dst = t;
    }
    if (tid == 0) rs_[0] = 0;
    if (own) rs_[tid + 1] = src[tid];
  }
  __syncthreads();
  // Deterministic CSR placement: slot = rs_[bus] + precomputed rank.
  // ev_ doubles as the per-edge diagonal-contribution stage (scan scratch dead).
  for (int l = tid; l < NLINE; l += NTH) {
    LineY L = line_y(I, l);
    int pf = rs_[L.f] + W->rank_f[l];
    int pt = rs_[L.t] + W->rank_t[l];
    cidx_[pf] = (unsigned short)L.t;
    fwd_[pf] = make_float2(L.ftr, L.fti);
    rev_[pf] = make_float2(L.tfr, L.tfi);
    ev_[pf]  = make_float2(L.ffr, L.ffi);
    cidx_[pt] = (unsigned short)L.f;
    fwd_[pt] = make_float2(L.tfr, L.tfi);
    rev_[pt] = make_float2(L.ftr, L.fti);
    ev_[pt]  = make_float2(L.ttr, L.tti);
  }
  __syncthreads();
  float Gkk = 0.f, Bkk = 0.f;
  int rs0 = 0, rs1 = 0;
  if (own) {
    rs0 = rs_[tid]; rs1 = rs_[tid + 1];
    double G = rdf(shg, tid, bf), B = rdf(shb, tid, bf);
    for (int e = rs0; e < rs1; ++e) { float2 d = ev_[e]; G += d.x; B += d.y; }
    Gkk = (float)G; Bkk = (float)B;
  }
  __syncthreads();   // diag reads done; ev_ free for edge values

  #define EDGE_JVP_S(SRC) \
    for (int k = 0; k < 4; ++k) { \
      int e = tid + k * NTH; \
      if (e < NE) { \
        int j = cidx_[e]; float2 f = fwd_[e], v = SRC[j]; \
        ev_[e] = make_float2(f.x * v.x - f.y * v.y, f.x * v.y + f.y * v.x); \
      } \
    }
  #define EDGE_VJP(SRC) \
    for (int k = 0; k < 4; ++k) { \
      int e = tid + k * NTH; \
      if (e < NE) { \
        int j = cidx_[e]; float2 r = rev_[e], w = SRC[j]; \
        ev_[e] = make_float2(r.x * w.x + r.y * w.y, r.x * w.y - r.y * w.x); \
      } \
    }
  #define EDGE_JVP_P() \
    for (int k = 0; k < 4; ++k) { \
      int e = tid + k * NTH; \
      if (e < NE) { \
        int j = cidx_[e]; float2 f = fwd_[e], vz = stz_[j], vq = stp_[j]; \
        float vx = vz.x + beta * vq.x, vy = vz.y + beta * vq.y; \
        ev_[e] = make_float2(f.x * vx - f.y * vy, f.x * vy + f.y * vx); \
      } \
    }

  double xvm = 1.0, xva = 0.0;
  int par = 0;
  double gabs = 0.0;   // absolute stopping floor, set from step 0's gamma0

  for (int outer = 0; outer < MAXSTEPS; ++outer) {
    // A: stage V (fp64 sincos -> correctly-rounded fp32 stage)
    float av = 0.f, bv = 0.f, ca = 1.f, sa = 0.f;
    if (own) {
      double Vm = (vp >= 0) ? xvm : (double)Vgb;
      double Va = (ap >= 0) ? xva : 0.0;
      double snd, csd;
      sincos(Va, &snd, &csd);
      ca = (float)csd; sa = (float)snd;
      av = (float)(Vm * csd); bv = (float)(Vm * snd);
      ab_[tid] = make_float2(av, bv);
    }
    __syncthreads();
    // B: edge products of I = Y V
    EDGE_JVP_S(ab_)
    __syncthreads();
    // C: currents, residual, Gram 2x2, stage g0 seeds (fp64 accumulation)
    float cI = 0.f, dI = 0.f, wPp = 0.f, wQq = 0.f;
    float M11 = 0.f, M12 = 0.f, M22 = 0.f;
    if (own) {
      double cId = (double)Gkk * av - (double)Bkk * bv;
      double dId = (double)Gkk * bv + (double)Bkk * av;
      for (int e = rs0; e < rs1; ++e) { float2 v = ev_[e]; cId += v.x; dId += v.y; }
      cI = (float)cId; dI = (float)dId;
      double P = (double)av * cId + (double)bv * dId - (double)Pspec;
      double Q = (double)bv * cId - (double)av * dId - (double)Qspec;
      wPp = (float)(mnr * P); wQq = (float)(mng * Q);
      sts_[tid] = make_float2(wPp * av + wQq * bv, wPp * bv - wQq * av);
      float w1r = ca * cI + sa * dI, w1i = sa * cI - ca * dI;
      float mr = Gkk * ca - Bkk * sa, mi = -(Gkk * sa + Bkk * ca);
      float ur0 = av * mr - bv * mi, ui0 = av * mi + bv * mr;
      float Tr = w1r + ur0, Ti = w1i + ui0;
      float w2r = av * dI - bv * cI, w2i = av * cI + bv * dI;
      float wr0 = Gkk * av - Bkk * bv, wi0 = Gkk * bv + Bkk * av;
      float zr0 = av * wr0 + bv * wi0, zi0 = bv * wr0 - av * wi0;
      float Uor = w2r + zi0, Uoi = w2i - zr0;
      float Avv = mnr * Tr * Tr + mng * Ti * Ti;
      float Aaa = mnr * Uor * Uor + mng * Uoi * Uoi;
      float Ava = mnr * Tr * Uor + mng * Ti * Uoi;
      for (int e = rs0; e < rs1; ++e) {
        int j = cidx_[e]; float2 r = rev_[e], vj = ab_[j], mj = mk_[j];
        float mrr = r.x * ca - r.y * sa, mii = -(r.x * sa + r.y * ca);
        float ur = vj.x * mrr - vj.y * mii, ui = vj.x * mii + vj.y * mrr;
        float wr = r.x * av - r.y * bv, wi = r.x * bv + r.y * av;
        float zr = vj.x * wr + vj.y * wi, zi = vj.y * wr - vj.x * wi;
        Avv += mj.x * ur * ur + mj.y * ui * ui;
        Aaa += mj.x * zi * zi + mj.y * zr * zr;
        Ava += mj.x * ur * zi - mj.y * ui * zr;
      }
      float A11 = Avv + RIDGE_F, A22 = Aaa + RIDGE_F;
      if (vp >= 0 && ap >= 0) {
        float id = 1.f / (A11 * A22 - Ava * Ava);
        M11 = A22 * id; M22 = A11 * id; M12 = -Ava * id;
      } else if (vp >= 0) M11 = 1.f / A11;
      else if (ap >= 0)  M22 = 1.f / A22;
    }
    __syncthreads();
    // D: edge-VJP of g0
    EDGE_VJP(sts_)
    __syncthreads();
    // E: g0 (fp64 rowsum), PCG init, stage T(z0), stp=0, beta=0
    float g0vm = 0.f, g0va = 0.f;
    if (own) {
      float cb = wPp * av + wQq * bv, db2 = wPp * bv - wQq * av;
      double sda = (double)wPp * cI - (double)wQq * dI + (double)Gkk * cb + (double)Bkk * db2;
      double sdb = (double)wPp * dI + (double)wQq * cI - (double)Bkk * cb + (double)Gkk * db2;
      for (int e = rs0; e < rs1; ++e) { float2 v = ev_[e]; sda += v.x; sdb += v.y; }
      g0vm = (float)(mng * (ca * sda + sa * sdb));
      g0va = (float)(mnr * (-bv * sda + av * sdb));
    }
    float rvm = g0vm, rva = g0va, dxvm = 0.f, dxva = 0.f;
    float zvm = M11 * rvm + M12 * rva, zva = M12 * rvm + M22 * rva;
    float pvm = 0.f, pva = 0.f;          // p enters loop as z + beta*p, beta=0
    float tzx = 0.f, tzy = 0.f, tpx = 0.f, tpy = 0.f;
    float beta = 0.f;
    if (own) {
      tzx = zvm * ca - zva * bv; tzy = zvm * sa + zva * av;
      stz_[tid] = make_float2(tzx, tzy);
      stp_[tid] = make_float2(0.f, 0.f);
    }
    float part = own ? (rvm * zvm + rva * zva) : 0.f;
    double gamma = (double)blk_sumf(part, red_[par]); par ^= 1;  // fences staging
    const double gamma0 = gamma;
    if (outer == 0) gabs = 0.1 * TOL_REL * gamma0;
    const double thr = fmax(gamma0 * TOL_REL, gabs);

    if (gamma0 > thr) {
      for (int it = 0; it < KCG_MAX; ++it) {
        // I1: edge-JVP of p_k = z_k + beta*p_{k-1} (dual-source)
        EDGE_JVP_P()
        __syncthreads();
        // I2: refresh p / T(p) (old stp reads fenced), rowsum, q seeds, delta
        float qP = 0.f, qQ = 0.f;
        float dpart = 0.f;
        if (own) {
          pvm = zvm + beta * pvm; pva = zva + beta * pva;
          tpx = tzx + beta * tpx; tpy = tzy + beta * tpy;
          stp_[tid] = make_float2(tpx, tpy);
          float dc = Gkk * tpx - Bkk * tpy, dd = Gkk * tpy + Bkk * tpx;
          for (int e = rs0; e < rs1; ++e) { float2 v = ev_[e]; dc += v.x; dd += v.y; }
          float dP = tpx * cI + av * dc + tpy * dI + bv * dd;
          float dQ = tpy * cI + bv * dc - tpx * dI - av * dd;
          qP = mnr * dP; qQ = mng * dQ;
          sts_[tid] = make_float2(qP * av + qQ * bv, qP * bv - qQ * av);
          dpart = qP * dP + qQ * dQ + RIDGE_F * (pvm * pvm + pva * pva);
        }
        double delta = (double)blk_sumf(dpart, red_[par]); par ^= 1;
        if (!(delta > 0.0)) break;
        float af = (float)(gamma / delta);
        // I3: edge-VJP of q
        EDGE_VJP(sts_)
        __syncthreads();
        // I4: rowsum, r/dx update, (RR), z, stage T(z), gamma-reduce
        if (own) {
          dxvm += af * pvm; dxva += af * pva;
          float cb = qP * av + qQ * bv, db2 = qP * bv - qQ * av;
          float sda = qP * cI - qQ * dI + Gkk * cb + Bkk * db2;
          float sdb = qP * dI + qQ * cI - Bkk * cb + Gkk * db2;
          for (int e = rs0; e < rs1; ++e) { float2 v = ev_[e]; sda += v.x; sdb += v.y; }
          float yvm = mng * (ca * sda + sa * sdb);
          float yva = mnr * (-bv * sda + av * sdb);
          rvm -= af * (yvm + RIDGE_F * pvm);
          rva -= af * (yva + RIDGE_F * pva);
        }
        if ((it & 63) == 63) {
          // residual replacement: r = g0 - (A + ridge) dx  (keep p)
          float tda = 0.f, tdb = 0.f;
          if (own) {
            tda = dxvm * ca - dxva * bv;
            tdb = dxvm * sa + dxva * av;
            sts_[tid] = make_float2(tda, tdb);
          }
          __syncthreads();   // all I4 rowsum reads of ev_ done
          EDGE_JVP_S(sts_)
          __syncthreads();
          float rqP = 0.f, rqQ = 0.f;
          if (own) {
            float dc = Gkk * tda - Bkk * tdb, dd = Gkk * tdb + Bkk * tda;
            for (int e = rs0; e < rs1; ++e) { float2 v = ev_[e]; dc += v.x; dd += v.y; }
            float dP = tda * cI + av * dc + tdb * dI + bv * dd;
            float dQ = tdb * cI + bv * dc - tda * dI - av * dd;
            rqP = mnr * dP; rqQ = mng * dQ;
            sts_[tid] = make_float2(rqP * av + rqQ * bv, rqP * bv - rqQ * av);
          }
          __syncthreads();
          EDGE_VJP(sts_)
          __syncthreads();
          if (own) {
            float cb = rqP * av + rqQ * bv, db2 = rqP * bv - rqQ * av;
            float sda = rqP * cI - rqQ * dI + Gkk * cb + Bkk * db2;
            float sdb = rqP * dI + rqQ * cI - Bkk * cb + Gkk * db2;
            for (int e = rs0; e < rs1; ++e) { float2 v = ev_[e]; sda += v.x; sdb += v.y; }
            float tvm = mng * (ca * sda + sa * sdb);
            float tva = mnr * (-bv * sda + av * sdb);
            rvm = g0vm - tvm - RIDGE_F * dxvm;
            rva = g0va - tva - RIDGE_F * dxva;
          }
        }
        float gpart = 0.f;
        if (own) {
          zvm = M11 * rvm + M12 * rva; zva = M12 * rvm + M22 * rva;
          tzx = zvm * ca - zva * bv; tzy = zvm * sa + zva * av;
          stz_[tid] = make_float2(tzx, tzy);
          gpart = rvm * zvm + rva * zva;
        }
        double gamma2 = (double)blk_sumf(gpart, red_[par]); par ^= 1;  // fences stz_
        if (gamma2 <= thr || !(gamma2 > 0.0)) break;
        beta = (float)(gamma2 / gamma);
        gamma = gamma2;
      }
    }
    if (own) { xvm -= (double)dxvm; xva -= (double)dxva; }
    __syncthreads();
  }

  // ---- final outputs ----
  float Vmf = 1.f, Vaf = 0.f, av = 0.f, bv = 0.f;
  if (own) {
    double Vm = (vp >= 0) ? xvm : (double)Vgb;
    double Va = (ap >= 0) ? xva : 0.0;
    double snd, csd;
    sincos(Va, &snd, &csd);
    Vmf = (float)Vm; Vaf = (float)Va;
    av = (float)(Vm * csd); bv = (float)(Vm * snd);
    ab_[tid] = make_float2(av, bv);
  }
  __syncthreads();
  EDGE_JVP_S(ab_)
  __syncthreads();
  float P = 0.f, Q = 0.f;
  if (own) {
    double cId = (double)Gkk * av - (double)Bkk * bv;
    double dId = (double)Gkk * bv + (double)Bkk * av;
    for (int e = rs0; e < rs1; ++e) { float2 v = ev_[e]; cId += v.x; dId += v.y; }
    P = (float)((double)av * cId + (double)bv * dId - (double)Pspec);
    Q = (float)((double)bv * cId - (double)av * dId - (double)Qspec);
    sts_[tid] = make_float2(P, Q);
  }
  __syncthreads();
  float rpart = own ? (mnr * P * P + mng * Q * Q) : 0.f;
  float rsum = blk_sumf(rpart, red_[par]); par ^= 1;
  if (own) {
    wrf(out, tid, Vmf, bf);
    wrf(out, NBUS + tid, Vaf, bf);
    float vmin = rdf(limits, 2 * tid, bf), vmax = rdf(limits, 2 * tid + 1, bf);
    float viol = fmaxf(Vmf - vmax, 0.f) + fmaxf(vmin - Vmf, 0.f);
    wrf(out, 2103 + tid, viol, bf);
  }
  if (tid < NGEN) wrf(out, 2000 + tid, sts_[gen_b[tid]].y, bf);
  if (tid == 0) {
    int ref = refp[0];
    wrf(out, 2100, sts_[ref].x, bf);
    wrf(out, 2101, sts_[ref].y, bf);
    wrf(out, 2102, rsum, bf);
  }
}

extern "C" void kernel_launch(void* const* d_in, const int* in_sizes, int n_in,
                              void* d_out, int out_size, void* d_ws, size_t ws_size,
                              hipStream_t stream) {
  const void* line_g   = d_in[0];
  const void* line_b   = d_in[1];
  const void* shunt_g  = d_in[2];
  const void* shunt_b  = d_in[3];
  const void* tap      = d_in[4];
  const void* shift    = d_in[5];
  const void* charging = d_in[6];
  const void* P_gen    = d_in[7];
  const void* V_gen    = d_in[8];
  const void* P_load   = d_in[9];
  const void* Q_load   = d_in[10];
  const void* limits   = d_in[11];
  const int* line_from = (const int*)d_in[12];
  const int* line_to   = (const int*)d_in[13];
  const int* gen_b     = (const int*)d_in[14];
  const int* load_b    = (const int*)d_in[15];
  const int* refp      = (const int*)d_in[18];

  if (ws_size < sizeof(Ws)) return;
  Ws* W = (Ws*)d_ws;

  setup_k<<<dim3(8), dim3(256), 0, stream>>>(line_g, P_gen, V_gen, P_load, Q_load,
                                             gen_b, load_b, refp,
                                             line_from, line_to, W);
  solver_k<<<dim3(1), dim3(NTH), 0, stream>>>(line_g, line_b, shunt_g, shunt_b,
                                              tap, shift, charging, limits,
                                              line_from, line_to, gen_b, refp,
                                              W, d_out);
}

// Round 2
// 1907.852 us; speedup vs baseline: 1.0237x; 1.0237x over previous
//
#include <hip/hip_runtime.h>
#include <hip/hip_bf16.h>

// ACOPF Gauss-Newton, matrix-free CGLS, single-workgroup LDS-resident solver.
// R16: cut inner-loop LDS traffic (bit-exact vs R15).
//  - I1 previously gathered TWO bus vectors per edge (stz_[j], stp_[j]) to
//    form p = z + beta*p per-edge, because beta is only known after the gamma
//    reduction. Now: after beta, do the recurrence per BUS in registers
//    (tp = tz + beta*tp) and stage only stp_; I1 is a single-gather JVP.
//    Removes 4096 b64 gathers + 1000 stz_ writes + per-edge beta-FMAs per CG
//    iteration; costs one extra __syncthreads. stz_ deleted (LDS 148->140KB).
//  - Bit-exact: tz + beta*tp per bus is the same expression/inputs as the old
//    per-edge vz + beta*vq, so the JVP consumes identical values and the
//    (chaotic) trajectory is unchanged -> absmax stays 0.1875.
//  - R15 determinism machinery unchanged: rank-based CSR placement, ordered
//    diag rowsum, fp64 Y build / sincos / outer rowsums, fp64 x-state.
// Measured R15: solver 1836 us, absmax 0.1875, SQ_LDS_BANK_CONFLICT 679K.

#define NBUS 1000
#define NLINE 2000
#define NE   (2*NLINE)
#define NGEN 100
#define NLOAD 500
#define NTH 1024
#define NWAVE (NTH/64)
#define MAXSTEPS 10
#define KCG_MAX 600
#define RIDGE_F 1e-6f
#define TOL_REL 1e-10

struct Ws {
  int   vm_pos[NBUS];
  int   va_pos[NBUS];
  float Pspec[NBUS];
  float Qspec[NBUS];
  float Vgb[NBUS];
  int   rank_f[NLINE];   // # earlier lines incident to lf[l]
  int   rank_t[NLINE];   // # earlier lines incident to lt[l]
};

__device__ __forceinline__ float rdf(const void* p, int i, int bf) {
  if (bf) {
    unsigned int u = ((unsigned int)(((const unsigned short*)p)[i])) << 16;
    return __uint_as_float(u);
  }
  return ((const float*)p)[i];
}
__device__ __forceinline__ void wrf(void* p, int i, float v, int bf) {
  if (bf) {
    unsigned int u = __float_as_uint(v);
    unsigned int r = (u + 0x7fffu + ((u >> 16) & 1u)) >> 16;  // RNE
    ((unsigned short*)p)[i] = (unsigned short)r;
  } else {
    ((float*)p)[i] = v;
  }
}
__device__ __forceinline__ int detect_bf(const void* p) {
  const unsigned short* h = (const unsigned short*)p;
  int ok = 1;
#pragma unroll
  for (int i = 0; i < 8; ++i) {
    float v = __uint_as_float(((unsigned int)h[i]) << 16);
    ok &= (v > 0.25f && v < 8.0f) ? 1 : 0;
  }
  return ok;
}
__device__ __forceinline__ int lbound(const int* a, int n, int v) {
  int lo = 0, hi = n;
  while (lo < hi) { int m = (lo + hi) >> 1; if (a[m] < v) lo = m + 1; else hi = m; }
  return lo;
}

struct In {
  const void *lg, *lb, *tp, *sh, *ch;
  const int *lf, *lt;
  int bf;
};
struct LineY { int f, t; float ffr, ffi, ttr, tti, ftr, fti, tfr, tfi; };

// fp64 build -> correctly-rounded fp32 Y entries (setup-only, runs twice/thread)
__device__ __forceinline__ LineY line_y(const In& I, int l) {
  LineY L;
  double g = rdf(I.lg, l, I.bf), b = rdf(I.lb, l, I.bf);
  double t = rdf(I.tp, l, I.bf), s = rdf(I.sh, l, I.bf);
  double c = rdf(I.ch, l, I.bf) * 0.5;
  double sn, cs;
  sincos(s, &sn, &cs);
  double it = 1.0 / t, it2 = it * it;
  L.f = I.lf[l]; L.t = I.lt[l];
  L.ffr = (float)(g * it2);                 L.ffi = (float)((b + c) * it2);
  L.ttr = (float)g;                         L.tti = (float)(b + c);
  L.ftr = (float)(-(g * cs - b * sn) * it); L.fti = (float)(-(g * sn + b * cs) * it);
  L.tfr = (float)(-(g * cs + b * sn) * it); L.tfi = (float)(-(b * cs - g * sn) * it);
  return L;
}

// fp32 block sum: 6-shuffle wave reduce, wave partials to LDS, tail = 4
// independent float4 reads. Deterministic (fixed order).
__device__ __forceinline__ float blk_sumf(float v, float* red) {
#pragma unroll
  for (int o = 32; o > 0; o >>= 1) v += __shfl_down(v, o, 64);
  if ((threadIdx.x & 63) == 0) red[threadIdx.x >> 6] = v;
  __syncthreads();
  const float4* r4 = (const float4*)red;
  float s = 0.f;
#pragma unroll
  for (int w = 0; w < NWAVE / 4; ++w) {
    float4 t = r4[w];
    s += t.x; s += t.y; s += t.z; s += t.w;
  }
  return s;
}

__global__ void setup_k(const void* lg, const void* Pg, const void* Vg,
                        const void* Pl, const void* Ql,
                        const int* gen_b, const int* load_b, const int* refp,
                        const int* lf, const int* lt,
                        Ws* __restrict__ W) {
  __shared__ int slf[NLINE], slt[NLINE];
  int bf = detect_bf(lg);
  int t = blockIdx.x * blockDim.x + threadIdx.x;
  for (int i = threadIdx.x; i < NLINE; i += blockDim.x) { slf[i] = lf[i]; slt[i] = lt[i]; }
  __syncthreads();
  int ref = refp[0];
  if (t < NBUS) {
    int gl = lbound(gen_b, NGEN, t);
    int isg = (gl < NGEN && gen_b[gl] == t) ? 1 : 0;
    int ll = lbound(load_b, NLOAD, t);
    int isl = (ll < NLOAD && load_b[ll] == t) ? 1 : 0;
    W->vm_pos[t] = isg ? -1 : (t - gl);
    W->va_pos[t] = (t == ref) ? -1 : (t - ((t > ref) ? 1 : 0));
    float ps = 0.f, qs = 0.f;
    if (isg) ps += rdf(Pg, gl, bf);
    if (isl) { ps += rdf(Pl, ll, bf); qs += rdf(Ql, ll, bf); }
    W->Pspec[t] = ps;
    W->Qspec[t] = qs;
    W->Vgb[t] = isg ? rdf(Vg, gl, bf) : 1.0f;
  }
  if (t < NLINE) {
    int f = slf[t], tt = slt[t], rf = 0, rt = 0;
    for (int l = 0; l < t; ++l) {
      int a = slf[l], b = slt[l];
      rf += (a == f) + (b == f);
      rt += (a == tt) + (b == tt);
    }
    W->rank_f[t] = rf;
    W->rank_t[t] = rt;
  }
}

__global__ void __launch_bounds__(NTH)
solver_k(const void* lg, const void* lb, const void* shg, const void* shb,
         const void* tp, const void* sh, const void* ch, const void* limits,
         const int* lf, const int* lt, const int* gen_b, const int* refp,
         const Ws* __restrict__ W, void* __restrict__ out) {
  __shared__ int rs_[NBUS + 1];
  __shared__ unsigned short cidx_[NE];  // edge -> source-bus index
  __shared__ float2 fwd_[NE];           // Y_kj for edge in row k
  __shared__ float2 rev_[NE];           // Y_jk
  __shared__ float2 ev_[NE];            // per-edge values (overlaid at setup)
  __shared__ float2 stp_[NBUS];         // T(p_k) per bus (single JVP source)
  __shared__ float2 sts_[NBUS];         // seed staging (q seeds / RR / outer)
  __shared__ float2 ab_[NBUS];          // per-bus V (re,im)
  __shared__ float2 mk_[NBUS];          // (mnr, mng)
  __shared__ __align__(16) float red_[2][NWAVE];

  const int tid = threadIdx.x;
  const bool own = (tid < NBUS);
  In I;
  I.lg = lg; I.lb = lb; I.tp = tp; I.sh = sh; I.ch = ch;
  I.lf = lf; I.lt = lt;
  I.bf = detect_bf(lg);
  const int bf = I.bf;

  // setup scratch overlaid on ev_ (dead after the scan completes)
  int* scanA = (int*)ev_;
  int* scanB = ((int*)ev_) + NTH;

  int vp = -1, ap = -1;
  float mng = 0.f, mnr = 0.f, Pspec = 0.f, Qspec = 0.f, Vgb = 1.f;
  if (own) {
    vp = W->vm_pos[tid]; ap = W->va_pos[tid];
    mng = (vp >= 0) ? 1.f : 0.f;
    mnr = (ap >= 0) ? 1.f : 0.f;
    Pspec = W->Pspec[tid]; Qspec = W->Qspec[tid]; Vgb = W->Vgb[tid];
    mk_[tid] = make_float2(mnr, mng);
  }
  scanA[tid] = 0;
  __syncthreads();
  for (int l = tid; l < NLINE; l += NTH) {   // integer atomics: order-independent
    atomicAdd(&scanA[lf[l]], 1);
    atomicAdd(&scanA[lt[l]], 1);
  }
  __syncthreads();
  {
    int* src = scanA; int* dst = scanB;
    for (int off = 1; off < NTH; off <<= 1) {
      int v = src[tid] + ((tid >= off) ? src[tid - off] : 0);
      dst[tid] = v;
      __syncthreads();
      int* t = src; src = dst; dst = t;
    }
    if (tid == 0) rs_[0] = 0;
    if (own) rs_[tid + 1] = src[tid];
  }
  __syncthreads();
  // Deterministic CSR placement: slot = rs_[bus] + precomputed rank.
  // ev_ doubles as the per-edge diagonal-contribution stage (scan scratch dead).
  for (int l = tid; l < NLINE; l += NTH) {
    LineY L = line_y(I, l);
    int pf = rs_[L.f] + W->rank_f[l];
    int pt = rs_[L.t] + W->rank_t[l];
    cidx_[pf] = (unsigned short)L.t;
    fwd_[pf] = make_float2(L.ftr, L.fti);
    rev_[pf] = make_float2(L.tfr, L.tfi);
    ev_[pf]  = make_float2(L.ffr, L.ffi);
    cidx_[pt] = (unsigned short)L.f;
    fwd_[pt] = make_float2(L.tfr, L.tfi);
    rev_[pt] = make_float2(L.ftr, L.fti);
    ev_[pt]  = make_float2(L.ttr, L.tti);
  }
  __syncthreads();
  float Gkk = 0.f, Bkk = 0.f;
  int rs0 = 0, rs1 = 0;
  if (own) {
    rs0 = rs_[tid]; rs1 = rs_[tid + 1];
    double G = rdf(shg, tid, bf), B = rdf(shb, tid, bf);
    for (int e = rs0; e < rs1; ++e) { float2 d = ev_[e]; G += d.x; B += d.y; }
    Gkk = (float)G; Bkk = (float)B;
  }
  __syncthreads();   // diag reads done; ev_ free for edge values

  #define EDGE_JVP_S(SRC) \
    for (int k = 0; k < 4; ++k) { \
      int e = tid + k * NTH; \
      if (e < NE) { \
        int j = cidx_[e]; float2 f = fwd_[e], v = SRC[j]; \
        ev_[e] = make_float2(f.x * v.x - f.y * v.y, f.x * v.y + f.y * v.x); \
      } \
    }
  #define EDGE_VJP(SRC) \
    for (int k = 0; k < 4; ++k) { \
      int e = tid + k * NTH; \
      if (e < NE) { \
        int j = cidx_[e]; float2 r = rev_[e], w = SRC[j]; \
        ev_[e] = make_float2(r.x * w.x + r.y * w.y, r.x * w.y - r.y * w.x); \
      } \
    }

  double xvm = 1.0, xva = 0.0;
  int par = 0;
  double gabs = 0.0;   // absolute stopping floor, set from step 0's gamma0

  for (int outer = 0; outer < MAXSTEPS; ++outer) {
    // A: stage V (fp64 sincos -> correctly-rounded fp32 stage)
    float av = 0.f, bv = 0.f, ca = 1.f, sa = 0.f;
    if (own) {
      double Vm = (vp >= 0) ? xvm : (double)Vgb;
      double Va = (ap >= 0) ? xva : 0.0;
      double snd, csd;
      sincos(Va, &snd, &csd);
      ca = (float)csd; sa = (float)snd;
      av = (float)(Vm * csd); bv = (float)(Vm * snd);
      ab_[tid] = make_float2(av, bv);
    }
    __syncthreads();
    // B: edge products of I = Y V
    EDGE_JVP_S(ab_)
    __syncthreads();
    // C: currents, residual, Gram 2x2, stage g0 seeds (fp64 accumulation)
    float cI = 0.f, dI = 0.f, wPp = 0.f, wQq = 0.f;
    float M11 = 0.f, M12 = 0.f, M22 = 0.f;
    if (own) {
      double cId = (double)Gkk * av - (double)Bkk * bv;
      double dId = (double)Gkk * bv + (double)Bkk * av;
      for (int e = rs0; e < rs1; ++e) { float2 v = ev_[e]; cId += v.x; dId += v.y; }
      cI = (float)cId; dI = (float)dId;
      double P = (double)av * cId + (double)bv * dId - (double)Pspec;
      double Q = (double)bv * cId - (double)av * dId - (double)Qspec;
      wPp = (float)(mnr * P); wQq = (float)(mng * Q);
      sts_[tid] = make_float2(wPp * av + wQq * bv, wPp * bv - wQq * av);
      float w1r = ca * cI + sa * dI, w1i = sa * cI - ca * dI;
      float mr = Gkk * ca - Bkk * sa, mi = -(Gkk * sa + Bkk * ca);
      float ur0 = av * mr - bv * mi, ui0 = av * mi + bv * mr;
      float Tr = w1r + ur0, Ti = w1i + ui0;
      float w2r = av * dI - bv * cI, w2i = av * cI + bv * dI;
      float wr0 = Gkk * av - Bkk * bv, wi0 = Gkk * bv + Bkk * av;
      float zr0 = av * wr0 + bv * wi0, zi0 = bv * wr0 - av * wi0;
      float Uor = w2r + zi0, Uoi = w2i - zr0;
      float Avv = mnr * Tr * Tr + mng * Ti * Ti;
      float Aaa = mnr * Uor * Uor + mng * Uoi * Uoi;
      float Ava = mnr * Tr * Uor + mng * Ti * Uoi;
      for (int e = rs0; e < rs1; ++e) {
        int j = cidx_[e]; float2 r = rev_[e], vj = ab_[j], mj = mk_[j];
        float mrr = r.x * ca - r.y * sa, mii = -(r.x * sa + r.y * ca);
        float ur = vj.x * mrr - vj.y * mii, ui = vj.x * mii + vj.y * mrr;
        float wr = r.x * av - r.y * bv, wi = r.x * bv + r.y * av;
        float zr = vj.x * wr + vj.y * wi, zi = vj.y * wr - vj.x * wi;
        Avv += mj.x * ur * ur + mj.y * ui * ui;
        Aaa += mj.x * zi * zi + mj.y * zr * zr;
        Ava += mj.x * ur * zi - mj.y * ui * zr;
      }
      float A11 = Avv + RIDGE_F, A22 = Aaa + RIDGE_F;
      if (vp >= 0 && ap >= 0) {
        float id = 1.f / (A11 * A22 - Ava * Ava);
        M11 = A22 * id; M22 = A11 * id; M12 = -Ava * id;
      } else if (vp >= 0) M11 = 1.f / A11;
      else if (ap >= 0)  M22 = 1.f / A22;
    }
    __syncthreads();
    // D: edge-VJP of g0
    EDGE_VJP(sts_)
    __syncthreads();
    // E: g0 (fp64 rowsum), PCG init, stage T(p0)=T(z0) (beta=0 recurrence)
    float g0vm = 0.f, g0va = 0.f;
    if (own) {
      float cb = wPp * av + wQq * bv, db2 = wPp * bv - wQq * av;
      double sda = (double)wPp * cI - (double)wQq * dI + (double)Gkk * cb + (double)Bkk * db2;
      double sdb = (double)wPp * dI + (double)wQq * cI - (double)Bkk * cb + (double)Gkk * db2;
      for (int e = rs0; e < rs1; ++e) { float2 v = ev_[e]; sda += v.x; sdb += v.y; }
      g0vm = (float)(mng * (ca * sda + sa * sdb));
      g0va = (float)(mnr * (-bv * sda + av * sdb));
    }
    float rvm = g0vm, rva = g0va, dxvm = 0.f, dxva = 0.f;
    float zvm = M11 * rvm + M12 * rva, zva = M12 * rvm + M22 * rva;
    float pvm = zvm, pva = zva;          // p0 = z0
    float tzx = 0.f, tzy = 0.f, tpx = 0.f, tpy = 0.f;
    if (own) {
      tzx = zvm * ca - zva * bv; tzy = zvm * sa + zva * av;
      tpx = tzx; tpy = tzy;
      stp_[tid] = make_float2(tpx, tpy);
    }
    float part = own ? (rvm * zvm + rva * zva) : 0.f;
    double gamma = (double)blk_sumf(part, red_[par]); par ^= 1;  // fences stp_
    const double gamma0 = gamma;
    if (outer == 0) gabs = 0.1 * TOL_REL * gamma0;
    const double thr = fmax(gamma0 * TOL_REL, gabs);

    if (gamma0 > thr) {
      for (int it = 0; it < KCG_MAX; ++it) {
        // I1: edge-JVP of T(p_k) (single gather; p-recurrence done in X)
        EDGE_JVP_S(stp_)
        __syncthreads();
        // I2: rowsum, q seeds, delta
        float qP = 0.f, qQ = 0.f;
        float dpart = 0.f;
        if (own) {
          float dc = Gkk * tpx - Bkk * tpy, dd = Gkk * tpy + Bkk * tpx;
          for (int e = rs0; e < rs1; ++e) { float2 v = ev_[e]; dc += v.x; dd += v.y; }
          float dP = tpx * cI + av * dc + tpy * dI + bv * dd;
          float dQ = tpy * cI + bv * dc - tpx * dI - av * dd;
          qP = mnr * dP; qQ = mng * dQ;
          sts_[tid] = make_float2(qP * av + qQ * bv, qP * bv - qQ * av);
          dpart = qP * dP + qQ * dQ + RIDGE_F * (pvm * pvm + pva * pva);
        }
        double delta = (double)blk_sumf(dpart, red_[par]); par ^= 1;
        if (!(delta > 0.0)) break;
        float af = (float)(gamma / delta);
        // I3: edge-VJP of q
        EDGE_VJP(sts_)
        __syncthreads();
        // I4: rowsum, r/dx update, (RR), z, gamma-reduce
        if (own) {
          dxvm += af * pvm; dxva += af * pva;
          float cb = qP * av + qQ * bv, db2 = qP * bv - qQ * av;
          float sda = qP * cI - qQ * dI + Gkk * cb + Bkk * db2;
          float sdb = qP * dI + qQ * cI - Bkk * cb + Gkk * db2;
          for (int e = rs0; e < rs1; ++e) { float2 v = ev_[e]; sda += v.x; sdb += v.y; }
          float yvm = mng * (ca * sda + sa * sdb);
          float yva = mnr * (-bv * sda + av * sdb);
          rvm -= af * (yvm + RIDGE_F * pvm);
          rva -= af * (yva + RIDGE_F * pva);
        }
        if ((it & 63) == 63) {
          // residual replacement: r = g0 - (A + ridge) dx  (keep p)
          float tda = 0.f, tdb = 0.f;
          if (own) {
            tda = dxvm * ca - dxva * bv;
            tdb = dxvm * sa + dxva * av;
            sts_[tid] = make_float2(tda, tdb);
          }
          __syncthreads();   // all I4 rowsum reads of ev_ done
          EDGE_JVP_S(sts_)
          __syncthreads();
          float rqP = 0.f, rqQ = 0.f;
          if (own) {
            float dc = Gkk * tda - Bkk * tdb, dd = Gkk * tdb + Bkk * tda;
            for (int e = rs0; e < rs1; ++e) { float2 v = ev_[e]; dc += v.x; dd += v.y; }
            float dP = tda * cI + av * dc + tdb * dI + bv * dd;
            float dQ = tdb * cI + bv * dc - tda * dI - av * dd;
            rqP = mnr * dP; rqQ = mng * dQ;
            sts_[tid] = make_float2(rqP * av + rqQ * bv, rqP * bv - rqQ * av);
          }
          __syncthreads();
          EDGE_VJP(sts_)
          __syncthreads();
          if (own) {
            float cb = rqP * av + rqQ * bv, db2 = rqP * bv - rqQ * av;
            float sda = rqP * cI - rqQ * dI + Gkk * cb + Bkk * db2;
            float sdb = rqP * dI + rqQ * cI - Bkk * cb + Gkk * db2;
            for (int e = rs0; e < rs1; ++e) { float2 v = ev_[e]; sda += v.x; sdb += v.y; }
            float tvm = mng * (ca * sda + sa * sdb);
            float tva = mnr * (-bv * sda + av * sdb);
            rvm = g0vm - tvm - RIDGE_F * dxvm;
            rva = g0va - tva - RIDGE_F * dxva;
          }
        }
        float gpart = 0.f;
        if (own) {
          zvm = M11 * rvm + M12 * rva; zva = M12 * rvm + M22 * rva;
          tzx = zvm * ca - zva * bv; tzy = zvm * sa + zva * av;
          gpart = rvm * zvm + rva * zva;
        }
        double gamma2 = (double)blk_sumf(gpart, red_[par]); par ^= 1;
        if (gamma2 <= thr || !(gamma2 > 0.0)) break;
        float bt = (float)(gamma2 / gamma);
        gamma = gamma2;
        // X: p-recurrence per bus (bit-identical to old per-edge z+beta*p),
        // stage T(p_{k+1}) as the single JVP source for the next I1.
        if (own) {
          pvm = zvm + bt * pvm; pva = zva + bt * pva;
          tpx = tzx + bt * tpx; tpy = tzy + bt * tpy;
          stp_[tid] = make_float2(tpx, tpy);
        }
        __syncthreads();   // fence stp_ before next I1's gathers
      }
    }
    if (own) { xvm -= (double)dxvm; xva -= (double)dxva; }
    __syncthreads();
  }

  // ---- final outputs ----
  float Vmf = 1.f, Vaf = 0.f, av = 0.f, bv = 0.f;
  if (own) {
    double Vm = (vp >= 0) ? xvm : (double)Vgb;
    double Va = (ap >= 0) ? xva : 0.0;
    double snd, csd;
    sincos(Va, &snd, &csd);
    Vmf = (float)Vm; Vaf = (float)Va;
    av = (float)(Vm * csd); bv = (float)(Vm * snd);
    ab_[tid] = make_float2(av, bv);
  }
  __syncthreads();
  EDGE_JVP_S(ab_)
  __syncthreads();
  float P = 0.f, Q = 0.f;
  if (own) {
    double cId = (double)Gkk * av - (double)Bkk * bv;
    double dId = (double)Gkk * bv + (double)Bkk * av;
    for (int e = rs0; e < rs1; ++e) { float2 v = ev_[e]; cId += v.x; dId += v.y; }
    P = (float)((double)av * cId + (double)bv * dId - (double)Pspec);
    Q = (float)((double)bv * cId - (double)av * dId - (double)Qspec);
    sts_[tid] = make_float2(P, Q);
  }
  __syncthreads();
  float rpart = own ? (mnr * P * P + mng * Q * Q) : 0.f;
  float rsum = blk_sumf(rpart, red_[par]); par ^= 1;
  if (own) {
    wrf(out, tid, Vmf, bf);
    wrf(out, NBUS + tid, Vaf, bf);
    float vmin = rdf(limits, 2 * tid, bf), vmax = rdf(limits, 2 * tid + 1, bf);
    float viol = fmaxf(Vmf - vmax, 0.f) + fmaxf(vmin - Vmf, 0.f);
    wrf(out, 2103 + tid, viol, bf);
  }
  if (tid < NGEN) wrf(out, 2000 + tid, sts_[gen_b[tid]].y, bf);
  if (tid == 0) {
    int ref = refp[0];
    wrf(out, 2100, sts_[ref].x, bf);
    wrf(out, 2101, sts_[ref].y, bf);
    wrf(out, 2102, rsum, bf);
  }
}

extern "C" void kernel_launch(void* const* d_in, const int* in_sizes, int n_in,
                              void* d_out, int out_size, void* d_ws, size_t ws_size,
                              hipStream_t stream) {
  const void* line_g   = d_in[0];
  const void* line_b   = d_in[1];
  const void* shunt_g  = d_in[2];
  const void* shunt_b  = d_in[3];
  const void* tap      = d_in[4];
  const void* shift    = d_in[5];
  const void* charging = d_in[6];
  const void* P_gen    = d_in[7];
  const void* V_gen    = d_in[8];
  const void* P_load   = d_in[9];
  const void* Q_load   = d_in[10];
  const void* limits   = d_in[11];
  const int* line_from = (const int*)d_in[12];
  const int* line_to   = (const int*)d_in[13];
  const int* gen_b     = (const int*)d_in[14];
  const int* load_b    = (const int*)d_in[15];
  const int* refp      = (const int*)d_in[18];

  if (ws_size < sizeof(Ws)) return;
  Ws* W = (Ws*)d_ws;

  setup_k<<<dim3(8), dim3(256), 0, stream>>>(line_g, P_gen, V_gen, P_load, Q_load,
                                             gen_b, load_b, refp,
                                             line_from, line_to, W);
  solver_k<<<dim3(1), dim3(NTH), 0, stream>>>(line_g, line_b, shunt_g, shunt_b,
                                              tap, shift, charging, limits,
                                              line_from, line_to, gen_b, refp,
                                              W, d_out);
}

// Round 4
// 1798.720 us; speedup vs baseline: 1.0858x; 1.0607x over previous
//
#include <hip/hip_runtime.h>
#include <hip/hip_bf16.h>

// ACOPF Gauss-Newton, matrix-free CGLS, single-workgroup LDS-resident solver.
// R18 = R16 (known-pass, 1781 us) + register-hoisted edge topology.
//  - R17 post-mortem: fusing the edge product into the accumulator changed
//    FMA contraction -> trajectory re-roll -> absmax 0.568 FAIL. Only
//    dataflow-preserving transforms are safe on this chaotic trajectory.
//  - R18: cidx_/fwd_/rev_ are loop-invariant; each thread's 4 static edge
//    slots are hoisted into registers ONCE. Edge phases keep the exact R16
//    structure (compute product -> store ev_[e] -> barrier -> owner rowsum
//    reads ev_) so every bit matches R16; only the operand source changes
//    (register copy vs LDS re-read). Removes ~12K constant-data LDS reads
//    per CG iteration. LDS arrays kept (C-phase Gram loop still uses them).
//  - R15/R16 determinism machinery unchanged: rank-based CSR placement,
//    ordered diag rowsum, fp64 Y build / sincos / outer rowsums, fp64 x.
// Measured R16: solver 1781 us, absmax 0.1875, SQ_LDS_BANK_CONFLICT 546K,
// VGPR 64. Expect R18: ~1550-1650 us, conflicts ~400K, VGPR ~84-96,
// absmax EXACTLY 0.1875 (else revert).

#define NBUS 1000
#define NLINE 2000
#define NE   (2*NLINE)
#define NGEN 100
#define NLOAD 500
#define NTH 1024
#define NWAVE (NTH/64)
#define MAXSTEPS 10
#define KCG_MAX 600
#define RIDGE_F 1e-6f
#define TOL_REL 1e-10

struct Ws {
  int   vm_pos[NBUS];
  int   va_pos[NBUS];
  float Pspec[NBUS];
  float Qspec[NBUS];
  float Vgb[NBUS];
  int   rank_f[NLINE];   // # earlier lines incident to lf[l]
  int   rank_t[NLINE];   // # earlier lines incident to lt[l]
};

__device__ __forceinline__ float rdf(const void* p, int i, int bf) {
  if (bf) {
    unsigned int u = ((unsigned int)(((const unsigned short*)p)[i])) << 16;
    return __uint_as_float(u);
  }
  return ((const float*)p)[i];
}
__device__ __forceinline__ void wrf(void* p, int i, float v, int bf) {
  if (bf) {
    unsigned int u = __float_as_uint(v);
    unsigned int r = (u + 0x7fffu + ((u >> 16) & 1u)) >> 16;  // RNE
    ((unsigned short*)p)[i] = (unsigned short)r;
  } else {
    ((float*)p)[i] = v;
  }
}
__device__ __forceinline__ int detect_bf(const void* p) {
  const unsigned short* h = (const unsigned short*)p;
  int ok = 1;
#pragma unroll
  for (int i = 0; i < 8; ++i) {
    float v = __uint_as_float(((unsigned int)h[i]) << 16);
    ok &= (v > 0.25f && v < 8.0f) ? 1 : 0;
  }
  return ok;
}
__device__ __forceinline__ int lbound(const int* a, int n, int v) {
  int lo = 0, hi = n;
  while (lo < hi) { int m = (lo + hi) >> 1; if (a[m] < v) lo = m + 1; else hi = m; }
  return lo;
}

struct In {
  const void *lg, *lb, *tp, *sh, *ch;
  const int *lf, *lt;
  int bf;
};
struct LineY { int f, t; float ffr, ffi, ttr, tti, ftr, fti, tfr, tfi; };

// fp64 build -> correctly-rounded fp32 Y entries (setup-only, runs twice/thread)
__device__ __forceinline__ LineY line_y(const In& I, int l) {
  LineY L;
  double g = rdf(I.lg, l, I.bf), b = rdf(I.lb, l, I.bf);
  double t = rdf(I.tp, l, I.bf), s = rdf(I.sh, l, I.bf);
  double c = rdf(I.ch, l, I.bf) * 0.5;
  double sn, cs;
  sincos(s, &sn, &cs);
  double it = 1.0 / t, it2 = it * it;
  L.f = I.lf[l]; L.t = I.lt[l];
  L.ffr = (float)(g * it2);                 L.ffi = (float)((b + c) * it2);
  L.ttr = (float)g;                         L.tti = (float)(b + c);
  L.ftr = (float)(-(g * cs - b * sn) * it); L.fti = (float)(-(g * sn + b * cs) * it);
  L.tfr = (float)(-(g * cs + b * sn) * it); L.tfi = (float)(-(b * cs - g * sn) * it);
  return L;
}

// fp32 block sum: 6-shuffle wave reduce, wave partials to LDS, tail = 4
// independent float4 reads. Deterministic (fixed order).
__device__ __forceinline__ float blk_sumf(float v, float* red) {
#pragma unroll
  for (int o = 32; o > 0; o >>= 1) v += __shfl_down(v, o, 64);
  if ((threadIdx.x & 63) == 0) red[threadIdx.x >> 6] = v;
  __syncthreads();
  const float4* r4 = (const float4*)red;
  float s = 0.f;
#pragma unroll
  for (int w = 0; w < NWAVE / 4; ++w) {
    float4 t = r4[w];
    s += t.x; s += t.y; s += t.z; s += t.w;
  }
  return s;
}

__global__ void setup_k(const void* lg, const void* Pg, const void* Vg,
                        const void* Pl, const void* Ql,
                        const int* gen_b, const int* load_b, const int* refp,
                        const int* lf, const int* lt,
                        Ws* __restrict__ W) {
  __shared__ int slf[NLINE], slt[NLINE];
  int bf = detect_bf(lg);
  int t = blockIdx.x * blockDim.x + threadIdx.x;
  for (int i = threadIdx.x; i < NLINE; i += blockDim.x) { slf[i] = lf[i]; slt[i] = lt[i]; }
  __syncthreads();
  int ref = refp[0];
  if (t < NBUS) {
    int gl = lbound(gen_b, NGEN, t);
    int isg = (gl < NGEN && gen_b[gl] == t) ? 1 : 0;
    int ll = lbound(load_b, NLOAD, t);
    int isl = (ll < NLOAD && load_b[ll] == t) ? 1 : 0;
    W->vm_pos[t] = isg ? -1 : (t - gl);
    W->va_pos[t] = (t == ref) ? -1 : (t - ((t > ref) ? 1 : 0));
    float ps = 0.f, qs = 0.f;
    if (isg) ps += rdf(Pg, gl, bf);
    if (isl) { ps += rdf(Pl, ll, bf); qs += rdf(Ql, ll, bf); }
    W->Pspec[t] = ps;
    W->Qspec[t] = qs;
    W->Vgb[t] = isg ? rdf(Vg, gl, bf) : 1.0f;
  }
  if (t < NLINE) {
    int f = slf[t], tt = slt[t], rf = 0, rt = 0;
    for (int l = 0; l < t; ++l) {
      int a = slf[l], b = slt[l];
      rf += (a == f) + (b == f);
      rt += (a == tt) + (b == tt);
    }
    W->rank_f[t] = rf;
    W->rank_t[t] = rt;
  }
}

__global__ void __launch_bounds__(NTH)
solver_k(const void* lg, const void* lb, const void* shg, const void* shb,
         const void* tp, const void* sh, const void* ch, const void* limits,
         const int* lf, const int* lt, const int* gen_b, const int* refp,
         const Ws* __restrict__ W, void* __restrict__ out) {
  __shared__ int rs_[NBUS + 1];
  __shared__ unsigned short cidx_[NE];  // edge -> source-bus index
  __shared__ float2 fwd_[NE];           // Y_kj for edge in row k
  __shared__ float2 rev_[NE];           // Y_jk
  __shared__ float2 ev_[NE];            // per-edge values (overlaid at setup)
  __shared__ float2 stp_[NBUS];         // T(p_k) per bus (single JVP source)
  __shared__ float2 sts_[NBUS];         // seed staging (q seeds / RR / outer)
  __shared__ float2 ab_[NBUS];          // per-bus V (re,im)
  __shared__ float2 mk_[NBUS];          // (mnr, mng)
  __shared__ __align__(16) float red_[2][NWAVE];

  const int tid = threadIdx.x;
  const bool own = (tid < NBUS);
  In I;
  I.lg = lg; I.lb = lb; I.tp = tp; I.sh = sh; I.ch = ch;
  I.lf = lf; I.lt = lt;
  I.bf = detect_bf(lg);
  const int bf = I.bf;

  // setup scratch overlaid on ev_ (dead after the scan completes)
  int* scanA = (int*)ev_;
  int* scanB = ((int*)ev_) + NTH;

  int vp = -1, ap = -1;
  float mng = 0.f, mnr = 0.f, Pspec = 0.f, Qspec = 0.f, Vgb = 1.f;
  if (own) {
    vp = W->vm_pos[tid]; ap = W->va_pos[tid];
    mng = (vp >= 0) ? 1.f : 0.f;
    mnr = (ap >= 0) ? 1.f : 0.f;
    Pspec = W->Pspec[tid]; Qspec = W->Qspec[tid]; Vgb = W->Vgb[tid];
    mk_[tid] = make_float2(mnr, mng);
  }
  scanA[tid] = 0;
  __syncthreads();
  for (int l = tid; l < NLINE; l += NTH) {   // integer atomics: order-independent
    atomicAdd(&scanA[lf[l]], 1);
    atomicAdd(&scanA[lt[l]], 1);
  }
  __syncthreads();
  {
    int* src = scanA; int* dst = scanB;
    for (int off = 1; off < NTH; off <<= 1) {
      int v = src[tid] + ((tid >= off) ? src[tid - off] : 0);
      dst[tid] = v;
      __syncthreads();
      int* t = src; src = dst; dst = t;
    }
    if (tid == 0) rs_[0] = 0;
    if (own) rs_[tid + 1] = src[tid];
  }
  __syncthreads();
  // Deterministic CSR placement: slot = rs_[bus] + precomputed rank.
  // ev_ doubles as the per-edge diagonal-contribution stage (scan scratch dead).
  for (int l = tid; l < NLINE; l += NTH) {
    LineY L = line_y(I, l);
    int pf = rs_[L.f] + W->rank_f[l];
    int pt = rs_[L.t] + W->rank_t[l];
    cidx_[pf] = (unsigned short)L.t;
    fwd_[pf] = make_float2(L.ftr, L.fti);
    rev_[pf] = make_float2(L.tfr, L.tfi);
    ev_[pf]  = make_float2(L.ffr, L.ffi);
    cidx_[pt] = (unsigned short)L.f;
    fwd_[pt] = make_float2(L.tfr, L.tfi);
    rev_[pt] = make_float2(L.ftr, L.fti);
    ev_[pt]  = make_float2(L.ttr, L.tti);
  }
  __syncthreads();
  float Gkk = 0.f, Bkk = 0.f;
  int rs0 = 0, rs1 = 0;
  if (own) {
    rs0 = rs_[tid]; rs1 = rs_[tid + 1];
    double G = rdf(shg, tid, bf), B = rdf(shb, tid, bf);
    for (int e = rs0; e < rs1; ++e) { float2 d = ev_[e]; G += d.x; B += d.y; }
    Gkk = (float)G; Bkk = (float)B;
  }
  __syncthreads();   // diag reads done; ev_ free for edge values

  // Register-hoisted edge topology: this thread's 4 static edge slots.
  // Pure copies of LDS contents -> operand values bit-identical to R16.
  int   ei_[4];
  float2 ef_[4], er_[4];
#pragma unroll
  for (int k = 0; k < 4; ++k) {
    int e = tid + k * NTH;
    if (e < NE) { ei_[k] = cidx_[e]; ef_[k] = fwd_[e]; er_[k] = rev_[e]; }
    else { ei_[k] = 0; ef_[k] = make_float2(0.f, 0.f); er_[k] = make_float2(0.f, 0.f); }
  }

  // Edge phases: identical structure/expressions to R16 (product -> ev_
  // store -> owner rowsum), operands from hoisted registers.
  #define EDGE_JVP_R(SRC) \
    _Pragma("unroll") \
    for (int k = 0; k < 4; ++k) { \
      int e = tid + k * NTH; \
      if (e < NE) { \
        int j = ei_[k]; float2 f = ef_[k], v = SRC[j]; \
        ev_[e] = make_float2(f.x * v.x - f.y * v.y, f.x * v.y + f.y * v.x); \
      } \
    }
  #define EDGE_VJP_R(SRC) \
    _Pragma("unroll") \
    for (int k = 0; k < 4; ++k) { \
      int e = tid + k * NTH; \
      if (e < NE) { \
        int j = ei_[k]; float2 r = er_[k], w = SRC[j]; \
        ev_[e] = make_float2(r.x * w.x + r.y * w.y, r.x * w.y - r.y * w.x); \
      } \
    }

  double xvm = 1.0, xva = 0.0;
  int par = 0;
  double gabs = 0.0;   // absolute stopping floor, set from step 0's gamma0

  for (int outer = 0; outer < MAXSTEPS; ++outer) {
    // A: stage V (fp64 sincos -> correctly-rounded fp32 stage)
    float av = 0.f, bv = 0.f, ca = 1.f, sa = 0.f;
    if (own) {
      double Vm = (vp >= 0) ? xvm : (double)Vgb;
      double Va = (ap >= 0) ? xva : 0.0;
      double snd, csd;
      sincos(Va, &snd, &csd);
      ca = (float)csd; sa = (float)snd;
      av = (float)(Vm * csd); bv = (float)(Vm * snd);
      ab_[tid] = make_float2(av, bv);
    }
    __syncthreads();
    // B: edge products of I = Y V
    EDGE_JVP_R(ab_)
    __syncthreads();
    // C: currents, residual, Gram 2x2, stage g0 seeds (fp64 accumulation)
    float cI = 0.f, dI = 0.f, wPp = 0.f, wQq = 0.f;
    float M11 = 0.f, M12 = 0.f, M22 = 0.f;
    if (own) {
      double cId = (double)Gkk * av - (double)Bkk * bv;
      double dId = (double)Gkk * bv + (double)Bkk * av;
      for (int e = rs0; e < rs1; ++e) { float2 v = ev_[e]; cId += v.x; dId += v.y; }
      cI = (float)cId; dI = (float)dId;
      double P = (double)av * cId + (double)bv * dId - (double)Pspec;
      double Q = (double)bv * cId - (double)av * dId - (double)Qspec;
      wPp = (float)(mnr * P); wQq = (float)(mng * Q);
      sts_[tid] = make_float2(wPp * av + wQq * bv, wPp * bv - wQq * av);
      float w1r = ca * cI + sa * dI, w1i = sa * cI - ca * dI;
      float mr = Gkk * ca - Bkk * sa, mi = -(Gkk * sa + Bkk * ca);
      float ur0 = av * mr - bv * mi, ui0 = av * mi + bv * mr;
      float Tr = w1r + ur0, Ti = w1i + ui0;
      float w2r = av * dI - bv * cI, w2i = av * cI + bv * dI;
      float wr0 = Gkk * av - Bkk * bv, wi0 = Gkk * bv + Bkk * av;
      float zr0 = av * wr0 + bv * wi0, zi0 = bv * wr0 - av * wi0;
      float Uor = w2r + zi0, Uoi = w2i - zr0;
      float Avv = mnr * Tr * Tr + mng * Ti * Ti;
      float Aaa = mnr * Uor * Uor + mng * Uoi * Uoi;
      float Ava = mnr * Tr * Uor + mng * Ti * Uoi;
      for (int e = rs0; e < rs1; ++e) {
        int j = cidx_[e]; float2 r = rev_[e], vj = ab_[j], mj = mk_[j];
        float mrr = r.x * ca - r.y * sa, mii = -(r.x * sa + r.y * ca);
        float ur = vj.x * mrr - vj.y * mii, ui = vj.x * mii + vj.y * mrr;
        float wr = r.x * av - r.y * bv, wi = r.x * bv + r.y * av;
        float zr = vj.x * wr + vj.y * wi, zi = vj.y * wr - vj.x * wi;
        Avv += mj.x * ur * ur + mj.y * ui * ui;
        Aaa += mj.x * zi * zi + mj.y * zr * zr;
        Ava += mj.x * ur * zi - mj.y * ui * zr;
      }
      float A11 = Avv + RIDGE_F, A22 = Aaa + RIDGE_F;
      if (vp >= 0 && ap >= 0) {
        float id = 1.f / (A11 * A22 - Ava * Ava);
        M11 = A22 * id; M22 = A11 * id; M12 = -Ava * id;
      } else if (vp >= 0) M11 = 1.f / A11;
      else if (ap >= 0)  M22 = 1.f / A22;
    }
    __syncthreads();
    // D: edge-VJP of g0
    EDGE_VJP_R(sts_)
    __syncthreads();
    // E: g0 (fp64 rowsum), PCG init, stage T(p0)=T(z0) (beta=0 recurrence)
    float g0vm = 0.f, g0va = 0.f;
    if (own) {
      float cb = wPp * av + wQq * bv, db2 = wPp * bv - wQq * av;
      double sda = (double)wPp * cI - (double)wQq * dI + (double)Gkk * cb + (double)Bkk * db2;
      double sdb = (double)wPp * dI + (double)wQq * cI - (double)Bkk * cb + (double)Gkk * db2;
      for (int e = rs0; e < rs1; ++e) { float2 v = ev_[e]; sda += v.x; sdb += v.y; }
      g0vm = (float)(mng * (ca * sda + sa * sdb));
      g0va = (float)(mnr * (-bv * sda + av * sdb));
    }
    float rvm = g0vm, rva = g0va, dxvm = 0.f, dxva = 0.f;
    float zvm = M11 * rvm + M12 * rva, zva = M12 * rvm + M22 * rva;
    float pvm = zvm, pva = zva;          // p0 = z0
    float tzx = 0.f, tzy = 0.f, tpx = 0.f, tpy = 0.f;
    if (own) {
      tzx = zvm * ca - zva * bv; tzy = zvm * sa + zva * av;
      tpx = tzx; tpy = tzy;
      stp_[tid] = make_float2(tpx, tpy);
    }
    float part = own ? (rvm * zvm + rva * zva) : 0.f;
    double gamma = (double)blk_sumf(part, red_[par]); par ^= 1;  // fences stp_
    const double gamma0 = gamma;
    if (outer == 0) gabs = 0.1 * TOL_REL * gamma0;
    const double thr = fmax(gamma0 * TOL_REL, gabs);

    if (gamma0 > thr) {
      for (int it = 0; it < KCG_MAX; ++it) {
        // I1: edge-JVP of T(p_k) (single gather; p-recurrence done in X)
        EDGE_JVP_R(stp_)
        __syncthreads();
        // I2: rowsum, q seeds, delta
        float qP = 0.f, qQ = 0.f;
        float dpart = 0.f;
        if (own) {
          float dc = Gkk * tpx - Bkk * tpy, dd = Gkk * tpy + Bkk * tpx;
          for (int e = rs0; e < rs1; ++e) { float2 v = ev_[e]; dc += v.x; dd += v.y; }
          float dP = tpx * cI + av * dc + tpy * dI + bv * dd;
          float dQ = tpy * cI + bv * dc - tpx * dI - av * dd;
          qP = mnr * dP; qQ = mng * dQ;
          sts_[tid] = make_float2(qP * av + qQ * bv, qP * bv - qQ * av);
          dpart = qP * dP + qQ * dQ + RIDGE_F * (pvm * pvm + pva * pva);
        }
        double delta = (double)blk_sumf(dpart, red_[par]); par ^= 1;
        if (!(delta > 0.0)) break;
        float af = (float)(gamma / delta);
        // I3: edge-VJP of q
        EDGE_VJP_R(sts_)
        __syncthreads();
        // I4: rowsum, r/dx update, (RR), z, gamma-reduce
        if (own) {
          dxvm += af * pvm; dxva += af * pva;
          float cb = qP * av + qQ * bv, db2 = qP * bv - qQ * av;
          float sda = qP * cI - qQ * dI + Gkk * cb + Bkk * db2;
          float sdb = qP * dI + qQ * cI - Bkk * cb + Gkk * db2;
          for (int e = rs0; e < rs1; ++e) { float2 v = ev_[e]; sda += v.x; sdb += v.y; }
          float yvm = mng * (ca * sda + sa * sdb);
          float yva = mnr * (-bv * sda + av * sdb);
          rvm -= af * (yvm + RIDGE_F * pvm);
          rva -= af * (yva + RIDGE_F * pva);
        }
        if ((it & 63) == 63) {
          // residual replacement: r = g0 - (A + ridge) dx  (keep p)
          float tda = 0.f, tdb = 0.f;
          if (own) {
            tda = dxvm * ca - dxva * bv;
            tdb = dxvm * sa + dxva * av;
            sts_[tid] = make_float2(tda, tdb);
          }
          __syncthreads();   // all I4 rowsum reads of ev_ done
          EDGE_JVP_R(sts_)
          __syncthreads();
          float rqP = 0.f, rqQ = 0.f;
          if (own) {
            float dc = Gkk * tda - Bkk * tdb, dd = Gkk * tdb + Bkk * tda;
            for (int e = rs0; e < rs1; ++e) { float2 v = ev_[e]; dc += v.x; dd += v.y; }
            float dP = tda * cI + av * dc + tdb * dI + bv * dd;
            float dQ = tdb * cI + bv * dc - tda * dI - av * dd;
            rqP = mnr * dP; rqQ = mng * dQ;
            sts_[tid] = make_float2(rqP * av + rqQ * bv, rqP * bv - rqQ * av);
          }
          __syncthreads();
          EDGE_VJP_R(sts_)
          __syncthreads();
          if (own) {
            float cb = rqP * av + rqQ * bv, db2 = rqP * bv - rqQ * av;
            float sda = rqP * cI - rqQ * dI + Gkk * cb + Bkk * db2;
            float sdb = rqP * dI + rqQ * cI - Bkk * cb + Gkk * db2;
            for (int e = rs0; e < rs1; ++e) { float2 v = ev_[e]; sda += v.x; sdb += v.y; }
            float tvm = mng * (ca * sda + sa * sdb);
            float tva = mnr * (-bv * sda + av * sdb);
            rvm = g0vm - tvm - RIDGE_F * dxvm;
            rva = g0va - tva - RIDGE_F * dxva;
          }
        }
        float gpart = 0.f;
        if (own) {
          zvm = M11 * rvm + M12 * rva; zva = M12 * rvm + M22 * rva;
          tzx = zvm * ca - zva * bv; tzy = zvm * sa + zva * av;
          gpart = rvm * zvm + rva * zva;
        }
        double gamma2 = (double)blk_sumf(gpart, red_[par]); par ^= 1;
        if (gamma2 <= thr || !(gamma2 > 0.0)) break;
        float bt = (float)(gamma2 / gamma);
        gamma = gamma2;
        // X: p-recurrence per bus (bit-identical to old per-edge z+beta*p),
        // stage T(p_{k+1}) as the single JVP source for the next I1.
        if (own) {
          pvm = zvm + bt * pvm; pva = zva + bt * pva;
          tpx = tzx + bt * tpx; tpy = tzy + bt * tpy;
          stp_[tid] = make_float2(tpx, tpy);
        }
        __syncthreads();   // fence stp_ before next I1's gathers
      }
    }
    if (own) { xvm -= (double)dxvm; xva -= (double)dxva; }
    __syncthreads();
  }

  // ---- final outputs ----
  float Vmf = 1.f, Vaf = 0.f, av = 0.f, bv = 0.f;
  if (own) {
    double Vm = (vp >= 0) ? xvm : (double)Vgb;
    double Va = (ap >= 0) ? xva : 0.0;
    double snd, csd;
    sincos(Va, &snd, &csd);
    Vmf = (float)Vm; Vaf = (float)Va;
    av = (float)(Vm * csd); bv = (float)(Vm * snd);
    ab_[tid] = make_float2(av, bv);
  }
  __syncthreads();
  EDGE_JVP_R(ab_)
  __syncthreads();
  float P = 0.f, Q = 0.f;
  if (own) {
    double cId = (double)Gkk * av - (double)Bkk * bv;
    double dId = (double)Gkk * bv + (double)Bkk * av;
    for (int e = rs0; e < rs1; ++e) { float2 v = ev_[e]; cId += v.x; dId += v.y; }
    P = (float)((double)av * cId + (double)bv * dId - (double)Pspec);
    Q = (float)((double)bv * cId - (double)av * dId - (double)Qspec);
    sts_[tid] = make_float2(P, Q);
  }
  __syncthreads();
  float rpart = own ? (mnr * P * P + mng * Q * Q) : 0.f;
  float rsum = blk_sumf(rpart, red_[par]); par ^= 1;
  if (own) {
    wrf(out, tid, Vmf, bf);
    wrf(out, NBUS + tid, Vaf, bf);
    float vmin = rdf(limits, 2 * tid, bf), vmax = rdf(limits, 2 * tid + 1, bf);
    float viol = fmaxf(Vmf - vmax, 0.f) + fmaxf(vmin - Vmf, 0.f);
    wrf(out, 2103 + tid, viol, bf);
  }
  if (tid < NGEN) wrf(out, 2000 + tid, sts_[gen_b[tid]].y, bf);
  if (tid == 0) {
    int ref = refp[0];
    wrf(out, 2100, sts_[ref].x, bf);
    wrf(out, 2101, sts_[ref].y, bf);
    wrf(out, 2102, rsum, bf);
  }
}

extern "C" void kernel_launch(void* const* d_in, const int* in_sizes, int n_in,
                              void* d_out, int out_size, void* d_ws, size_t ws_size,
                              hipStream_t stream) {
  const void* line_g   = d_in[0];
  const void* line_b   = d_in[1];
  const void* shunt_g  = d_in[2];
  const void* shunt_b  = d_in[3];
  const void* tap      = d_in[4];
  const void* shift    = d_in[5];
  const void* charging = d_in[6];
  const void* P_gen    = d_in[7];
  const void* V_gen    = d_in[8];
  const void* P_load   = d_in[9];
  const void* Q_load   = d_in[10];
  const void* limits   = d_in[11];
  const int* line_from = (const int*)d_in[12];
  const int* line_to   = (const int*)d_in[13];
  const int* gen_b     = (const int*)d_in[14];
  const int* load_b    = (const int*)d_in[15];
  const int* refp      = (const int*)d_in[18];

  if (ws_size < sizeof(Ws)) return;
  Ws* W = (Ws*)d_ws;

  setup_k<<<dim3(8), dim3(256), 0, stream>>>(line_g, P_gen, V_gen, P_load, Q_load,
                                             gen_b, load_b, refp,
                                             line_from, line_to, W);
  solver_k<<<dim3(1), dim3(NTH), 0, stream>>>(line_g, line_b, shunt_g, shunt_b,
                                              tap, shift, charging, limits,
                                              line_from, line_to, gen_b, refp,
                                              W, d_out);
}